// Round 9
// baseline (268.603 us; speedup 1.0000x reference)
//
#include <hip/hip_runtime.h>
#include <stdint.h>

typedef unsigned short ushort_t;
typedef _Float16 f16x8 __attribute__((ext_vector_type(8)));
typedef _Float16 f16x4 __attribute__((ext_vector_type(4)));
typedef float f32x4 __attribute__((ext_vector_type(4)));
typedef float f32x16 __attribute__((ext_vector_type(16)));
typedef int   i32x4 __attribute__((ext_vector_type(4)));
typedef int   i32x16 __attribute__((ext_vector_type(16)));
typedef unsigned int uint4v __attribute__((ext_vector_type(4)));

#define HW_ 16384
#define MFMAH  __builtin_amdgcn_mfma_f32_32x32x16_f16
#define MFMAI8 __builtin_amdgcn_mfma_i32_32x32x32_i8
#define C_CORR (1.0f/16777216.0f)   // 2^-24: Al8(2^15)*Wh8(2^9) and Ah8(2^4)*Wl8(2^20)

__device__ __forceinline__ ushort_t f2h_bits(float f){
  union { _Float16 h; ushort_t u; } c; c.h = (_Float16)f; return c.u;
}
__device__ __forceinline__ float h_bits2f(ushort_t u){
  union { _Float16 h; ushort_t u; } c; c.u = u; return (float)c.h;
}
__device__ __forceinline__ int clamp8(int v){ return min(max(v,-127),127); }

// async global->LDS DMA, 16B per lane: global src is per-lane, LDS dest is
// wave-uniform base + lane*16 (HW rule). Tracked by vmcnt.
__device__ __forceinline__ void gload_lds16(const void* g, void* l){
  __builtin_amdgcn_global_load_lds(
      (const __attribute__((address_space(1))) unsigned int*)g,
      (__attribute__((address_space(3))) unsigned int*)l, 16, 0, 0);
}

// ---------------------------------------------------------------------------
// WpH (f16 bits): ((conv*2+mh)*36 + ks16)*512 + lane*8 + j
//   conv 0=Ws 1=Wx 2=Wy; co = mh*32+(lane&31); tap = ks16>>2;
//   ci = (ks16&3)*16 + (lane>>5)*8 + j.
// WpC (i8 dwords): ((g*2+mh)*18 + ks32)*256 + lane*4 + j4
//   g 0=Wh8x 1=Wh8y 2=Wl8x 3=Wl8y; tap = ks32>>1;
//   ci = (ks32&1)*32 + (lane>>5)*16 + j4*4 + bb.
// ---------------------------------------------------------------------------
__global__ __launch_bounds__(256) void k_repack(
    const float* __restrict__ Ws, const float* __restrict__ Wx,
    const float* __restrict__ Wy,
    ushort_t* __restrict__ WpH, unsigned int* __restrict__ WpC){
  int e = blockIdx.x*256 + threadIdx.x;
  if (e < 110592){
    int j = e & 7; int lane = (e >> 3) & 63; int rest = e >> 9;
    int ks = rest % 36; int cm = rest / 36;
    int conv = cm >> 1; int mh = cm & 1;
    int co = mh*32 + (lane & 31);
    int tap = ks >> 2;
    int ci = (ks & 3)*16 + ((lane >> 5) & 1)*8 + j;
    const float* src = (conv==0) ? Ws : (conv==1) ? Wx : Wy;
    WpH[e] = f2h_bits(src[(co*64 + ci)*9 + tap]);
  } else if (e < 110592 + 36864){
    int d = e - 110592;
    int j4 = d & 3; int lane = (d >> 2) & 63; int rest = d >> 8;
    int ks = rest % 18; int gm = rest / 18;
    int g = gm >> 1; int mh = gm & 1;
    int co = mh*32 + (lane & 31);
    int tap = ks >> 1;
    const float* src = (g==0 || g==2) ? Wx : Wy;
    unsigned dd = 0;
    #pragma unroll
    for (int bb=0; bb<4; bb++){
      int ci = (ks & 1)*32 + ((lane >> 5) & 1)*16 + j4*4 + bb;
      float w = src[(co*64 + ci)*9 + tap];
      int v;
      if (g < 2){
        v = clamp8((int)rintf(w*512.f));
      } else {
        float wl = w - h_bits2f(f2h_bits(w));
        v = clamp8((int)rintf(wl*1048576.f));
      }
      dd |= ((unsigned)(v & 255)) << (bb*8);
    }
    WpC[d] = dd;
  }
}

// ---------------------------------------------------------------------------
// Fused conv. R8 model: per CU-iter wall ~4500 cyc vs 1280 MFMA; the gap is
// the 10 SYNCHRONOUS 16B weight loads/wave/iter (L2 latency exposed at
// 2 waves/SIMD; MfmaUtil==VALUBusy in every round -> addressing VALU small).
// Fix: double-buffered ASYNC weight staging via global_load_lds (m97
// pattern). Weights are laid out base+lane*16 -> DMA lane-linear LDS write
// fits exactly. Per iter: 20 chunks x 1KB staged ONCE per CU; waves read
// conflict-free stride-16 ds_read_b128 (hideable). Issue next-iter chunks
// BEFORE compute; vmcnt(0)+barrier per iter (1280 cyc MFMA hides the DMA).
// Identical values, identical MFMA order -> bit-identical output.
// LDS: inputs 87040 + weights 2x20KB = 127 KB -> 1 block/CU, 8 waves.
// NT stores on score/coords (R7). Coords encode (i+4)*480 (R8 sampler).
// Grid 1024 XCD-swizzled: all WGs of batch b on XCD b&7.
// ---------------------------------------------------------------------------
__global__ __launch_bounds__(512, 2) void k_conv_all(
    const float* __restrict__ x,
    const ushort_t* __restrict__ WpH, const unsigned int* __restrict__ WpC,
    const float* __restrict__ bs, const float* __restrict__ bx,
    const float* __restrict__ by,
    ushort_t* __restrict__ score, unsigned int* __restrict__ coords){
  int bid = blockIdx.x;
  int idx = bid >> 3;
  int b = (bid & 7) + 8*(idx >> 6);     // 64 blocks per batch
  int rest = idx & 63;
  int h0 = (rest >> 2)*8;               // 16 h-tiles of 8 rows
  int wq = (rest & 3)*32;
  int t = threadIdx.x; int lane = t & 63; int wid = t >> 6;   // wid 0..7
  int n = lane & 31; int kh = lane >> 5;
  __shared__ __align__(16) _Float16 BH[10*34*64];   // 43520 B
  __shared__ __align__(16) char BAl[10*34*64];      // 21760 B
  __shared__ __align__(16) char BAh[10*34*64];      // 21760 B
  __shared__ __align__(16) char WL[2][20][1024];    // 40960 B weight dbuf

  // chunk c (0..19): mh2 = c/10; frag = c%10. frag 0..5 -> f16 (conv=frag>>1,
  // half=frag&1), src off ((conv*2+mh2)*36 + 2*ks + half)*1024 B in WpH.
  // frag 6..9 -> i8 g=frag-6, src off ((g*2+mh2)*18 + ks)*1024 B in WpC.
  #define STAGE_W(KS, BB) do {                                           \
    for (int c = wid; c < 20; c += 8){                                   \
      int mh2 = (c >= 10) ? 1 : 0; int frag = c - mh2*10;                \
      const char* srcp;                                                  \
      if (frag < 6){ int cv = frag >> 1; int hf = frag & 1;              \
        srcp = (const char*)WpH + ((cv*2+mh2)*36 + 2*(KS) + hf)*1024;    \
      } else { int g = frag - 6;                                         \
        srcp = (const char*)WpC + ((g*2+mh2)*18 + (KS))*1024;            \
      }                                                                  \
      gload_lds16(srcp + (size_t)lane*16, &WL[BB][c][0]);                \
    }                                                                    \
  } while(0)

  // prologue: kick off weight DMA for ks=0 (lands during input staging)
  STAGE_W(0, 0);

  // ---- staging: 1360 items of 16 ci (10 rows x 4 q x 34 w1), 3 passes ----
  const float* xb = x + (size_t)b*64*HW_;
  #pragma unroll
  for (int it=0; it<3; it++){
    int f = it*512 + t;
    if (f < 1360){
      int r = f/136; int rem = f - r*136; int q = rem/34; int w1 = rem - q*34;
      int y = h0 + r - 1; int w = wq + w1 - 1;
      f16x8 h0v = {0,0,0,0,0,0,0,0}, h1v = {0,0,0,0,0,0,0,0};
      unsigned alb[4] = {0,0,0,0}, ahb[4] = {0,0,0,0};
      if (((unsigned)y < 128u) & ((unsigned)w < 128u)){
        const float* p = xb + (size_t)(q*16)*HW_ + y*128 + w;
        #pragma unroll
        for (int j=0; j<16; j++){
          float v = p[(size_t)j*HW_];
          _Float16 hv = (_Float16)v;
          float al = v - (float)hv;
          int a8 = clamp8((int)rintf(al*32768.f));
          int x8 = clamp8((int)rintf(v*16.f));
          if (j < 8) h0v[j] = hv; else h1v[j-8] = hv;
          alb[j>>2] |= ((unsigned)(a8 & 255)) << ((j&3)*8);
          ahb[j>>2] |= ((unsigned)(x8 & 255)) << ((j&3)*8);
        }
      }
      int base = (r*34 + w1)*64;
      int sw = w1 & 7;
      *(f16x8*)&BH[base + (((2*q)   ^ sw) << 3)] = h0v;
      *(f16x8*)&BH[base + (((2*q+1) ^ sw) << 3)] = h1v;
      int islot = ((q + (w1 >> 1)) & 3) << 4;
      i32x4 av  = {(int)alb[0],(int)alb[1],(int)alb[2],(int)alb[3]};
      i32x4 hv2 = {(int)ahb[0],(int)ahb[1],(int)ahb[2],(int)ahb[3]};
      *(i32x4*)&BAl[base + islot] = av;
      *(i32x4*)&BAh[base + islot] = hv2;
    }
  }
  asm volatile("s_waitcnt vmcnt(0)" ::: "memory");
  __syncthreads();

  int mh = wid & 1;      // co half
  int pp = wid >> 1;     // row-pair within tile (0..3)

  f32x16 acc_s0, acc_gx0, acc_gy0, acc_s1, acc_gx1, acc_gy1;
  i32x16 c_x0, c_y0, c_x1, c_y1;
  #pragma unroll
  for (int r2=0; r2<16; r2++){
    acc_s0[r2]=0.f; acc_gx0[r2]=0.f; acc_gy0[r2]=0.f;
    acc_s1[r2]=0.f; acc_gx1[r2]=0.f; acc_gy1[r2]=0.f;
    c_x0[r2]=0; c_y0[r2]=0; c_x1[r2]=0; c_y1[r2]=0;
  }

  int wbase = mh*10;     // this wave's weight chunk group

  // one weight fetch -> MFMAs for BOTH rows of this wave's pair
  #define ROWBLK(ROWB, AS_, AX_, AY_, CX_, CY_) do {                    \
    f16x8 bA  = *(const f16x8*)&BH[(ROWB) + off0];                      \
    f16x8 bB  = *(const f16x8*)&BH[(ROWB) + off1];                      \
    i32x4 bal = *(const i32x4*)&BAl[(ROWB) + islot];                    \
    i32x4 bah = *(const i32x4*)&BAh[(ROWB) + islot];                    \
    AS_ = MFMAH(sA, bA, AS_, 0,0,0);                                    \
    AX_ = MFMAH(xA, bA, AX_, 0,0,0);                                    \
    AY_ = MFMAH(yA, bA, AY_, 0,0,0);                                    \
    AS_ = MFMAH(sB, bB, AS_, 0,0,0);                                    \
    AX_ = MFMAH(xB, bB, AX_, 0,0,0);                                    \
    AY_ = MFMAH(yB, bB, AY_, 0,0,0);                                    \
    CX_ = MFMAI8(whx, bal, CX_, 0,0,0);                                 \
    CX_ = MFMAI8(wlx, bah, CX_, 0,0,0);                                 \
    CY_ = MFMAI8(why, bal, CY_, 0,0,0);                                 \
    CY_ = MFMAI8(wly, bah, CY_, 0,0,0);                                 \
  } while(0)

  int buf = 0;
  #pragma unroll 1
  for (int ks=0; ks<18; ++ks){
    // issue next-iter weight DMA first: hides under this iter's MFMA
    if (ks < 17) STAGE_W(ks+1, buf^1);
    int tap = ks >> 1; int qp = ks & 1;
    int rb = tap/3; int dw = tap - rb*3 - 1;
    int w1 = n + dw + 1;                    // 0..33
    int sw = w1 & 7;
    int rowb0 = ((rb + 2*pp)*34 + w1)*64;   // LDS row for output row 2*pp
    int rowb1 = rowb0 + 34*64;              // output row 2*pp+1
    int off0  = ((qp*4 + kh)     ^ sw) << 3;
    int off1  = ((qp*4 + 2 + kh) ^ sw) << 3;
    int islot = (((qp*2 + kh) + (w1 >> 1)) & 3) << 4;
    const char* wb = &WL[buf][wbase][0];
    f16x8 sA = *(const f16x8*)(wb + 0*1024 + lane*16);
    f16x8 sB = *(const f16x8*)(wb + 1*1024 + lane*16);
    f16x8 xA = *(const f16x8*)(wb + 2*1024 + lane*16);
    f16x8 xB = *(const f16x8*)(wb + 3*1024 + lane*16);
    f16x8 yA = *(const f16x8*)(wb + 4*1024 + lane*16);
    f16x8 yB = *(const f16x8*)(wb + 5*1024 + lane*16);
    i32x4 whx = *(const i32x4*)(wb + 6*1024 + lane*16);
    i32x4 why = *(const i32x4*)(wb + 7*1024 + lane*16);
    i32x4 wlx = *(const i32x4*)(wb + 8*1024 + lane*16);
    i32x4 wly = *(const i32x4*)(wb + 9*1024 + lane*16);
    ROWBLK(rowb0, acc_s0, acc_gx0, acc_gy0, c_x0, c_y0);
    ROWBLK(rowb1, acc_s1, acc_gx1, acc_gy1, c_x1, c_y1);
    // drain own DMAs (issued ~1280 MFMA-cycles ago) + publish to all waves
    asm volatile("s_waitcnt vmcnt(0)" ::: "memory");
    __syncthreads();
    buf ^= 1;
  }
  #undef ROWBLK
  #undef STAGE_W

  // epilogue: score f16 + packed u16 coords ((i+4)*480 exact shift for the
  // padded-plane sampler). NT stores keep the write stream out of L2.
  int w = wq + n;
  int hb = h0 + 2*pp;
  #define EPILOG(AS_, AX_, AY_, CX_, CY_, H_) do {                      \
    ushort_t*     sb = score  + (size_t)b*64*HW_ + (H_)*128 + w;        \
    unsigned int* cb = coords + (size_t)b*64*HW_ + (H_)*128 + w;        \
    _Pragma("unroll")                                                   \
    for (int reg=0; reg<16; reg++){                                     \
      int col = mh*32 + (reg & 3) + 8*(reg >> 2) + 4*kh;                \
      float sv = AS_[reg] + bs[col];                                    \
      float gx = AX_[reg] + (float)CX_[reg]*C_CORR + bx[col];           \
      float gy = AY_[reg] + (float)CY_[reg]*C_CORR + by[col];           \
      __builtin_nontemporal_store(f2h_bits(sv), &sb[(size_t)col*HW_]);  \
      float ixf = fminf(fmaxf((gx + 1.f)*64.f - 0.5f, -2.f), 129.f);    \
      float iyf = fminf(fmaxf((gy + 1.f)*64.f - 0.5f, -2.f), 129.f);    \
      unsigned ux = (unsigned)rintf((ixf + 4.f)*480.f);                 \
      unsigned uy = (unsigned)rintf((iyf + 4.f)*480.f);                 \
      __builtin_nontemporal_store(ux | (uy << 16), &cb[(size_t)col*HW_]); \
    }                                                                   \
  } while(0)
  EPILOG(acc_s0, acc_gx0, acc_gy0, c_x0, c_y0, hb);
  EPILOG(acc_s1, acc_gx1, acc_gy1, c_x1, c_y1, hb+1);
  #undef EPILOG
}

// ---------------------------------------------------------------------------
// Sampler v2: zero-padded LDS plane -> branchless, maskless bilinear.
// Plane: 135 rows x 136 u16 (stride 68 dwords), interior at [y+4][x+4],
// borders zero (== grid_sample zeros padding). Coords are (i+4)*480 u16.
// 36720 B LDS -> 4 blocks/CU. Grid 1024 XCD-swizzled.
// ---------------------------------------------------------------------------
__global__ __launch_bounds__(256, 4) void k_sample(
    const ushort_t* __restrict__ score, const unsigned int* __restrict__ coords,
    float* __restrict__ out){
  int bid = blockIdx.x;
  int idx = bid >> 3;
  int b  = (bid & 7) + 8*(idx >> 6);
  int co = idx & 63;
  int t = threadIdx.x;
  __shared__ __align__(16) unsigned int SC32[135*68];   // 36720 B

  // zero-fill whole plane (borders must be 0; interior overwritten below)
  #pragma unroll
  for (int i=0;i<9;i++){
    int c = i*256 + t;
    if (c < 2295){
      uint4v z = {0,0,0,0};
      *(uint4v*)&SC32[c*4] = z;
    }
  }
  __syncthreads();

  const ushort_t* sp = score + (size_t)(b*64 + co)*HW_;
  ushort_t* scu = (ushort_t*)SC32;
  #pragma unroll
  for (int i=0;i<8;i++){
    int c = i*256 + t;
    int y = c >> 4; int xg = (c & 15)*8;
    f16x8 v = __builtin_nontemporal_load((const f16x8*)(sp + c*8));
    f16x4 lo = {v[0],v[1],v[2],v[3]};
    f16x4 hi = {v[4],v[5],v[6],v[7]};
    *(f16x4*)&scu[(y+4)*136 + (xg+4)] = lo;   // 8B-aligned ds_write_b64
    *(f16x4*)&scu[(y+4)*136 + (xg+8)] = hi;
  }
  __syncthreads();

  const unsigned int* cp = coords + (size_t)(b*64 + co)*HW_;
  float* op = out + (size_t)(b*64 + co)*HW_;
  uint4v ca  = __builtin_nontemporal_load((const uint4v*)(cp + t*8));
  uint4v cb2 = __builtin_nontemporal_load((const uint4v*)(cp + t*8 + 4));
  #pragma unroll 1
  for (int k=0;k<8;k++){
    int px = (k*256 + t)*8;
    uint4v na, nb;
    if (k < 7){
      na = __builtin_nontemporal_load((const uint4v*)(cp + px + 2048));
      nb = __builtin_nontemporal_load((const uint4v*)(cp + px + 2052));
    }
    float r[8];
    #pragma unroll
    for (int j=0;j<8;j++){
      unsigned u = (j < 4) ? ca[j] : cb2[j-4];
      float ixp = (float)(u & 0xffffu)*(1.0f/480.0f);   // padded coord [2,133]
      float iyp = (float)(u >> 16)   *(1.0f/480.0f);
      float x0f = floorf(ixp), y0f = floorf(iyp);
      int x0 = (int)x0f, y0 = (int)y0f;                 // 2..133, always valid
      float wx1 = ixp - x0f, wy1 = iyp - y0f;
      float wx0 = 1.f - wx1, wy0 = 1.f - wy1;
      int base = y0*68 + (x0 >> 1);
      unsigned d00 = SC32[base],    d01 = SC32[base+1];
      unsigned d10 = SC32[base+68], d11 = SC32[base+69];
      unsigned sh = (unsigned)(x0 & 1) << 4;
      unsigned p0 = (unsigned)(((((unsigned long long)d01) << 32) | d00) >> sh);
      unsigned p1 = (unsigned)(((((unsigned long long)d11) << 32) | d10) >> sh);
      float v00 = h_bits2f((ushort_t)(p0 & 0xffffu));
      float v01 = h_bits2f((ushort_t)(p0 >> 16));
      float v10 = h_bits2f((ushort_t)(p1 & 0xffffu));
      float v11 = h_bits2f((ushort_t)(p1 >> 16));
      r[j] = wy0*(v00*wx0 + v01*wx1) + wy1*(v10*wx0 + v11*wx1);
    }
    f32x4 r0 = {r[0],r[1],r[2],r[3]};
    f32x4 r1 = {r[4],r[5],r[6],r[7]};
    __builtin_nontemporal_store(r0, (f32x4*)(op + px));
    __builtin_nontemporal_store(r1, (f32x4*)(op + px + 4));
    ca = na; cb2 = nb;
  }
}

// ---------------------------------------------------------------------------
extern "C" void kernel_launch(void* const* d_in, const int* in_sizes, int n_in,
                              void* d_out, int out_size, void* d_ws, size_t ws_size,
                              hipStream_t stream){
  const float* x  = (const float*)d_in[0];
  const float* Ws = (const float*)d_in[1];
  const float* bs = (const float*)d_in[2];
  const float* Wx = (const float*)d_in[3];
  const float* bx = (const float*)d_in[4];
  const float* Wy = (const float*)d_in[5];
  const float* by = (const float*)d_in[6];
  float* out = (float*)d_out;
  ushort_t* ws  = (ushort_t*)d_ws;
  ushort_t*     score  = ws;                                   // 33.5 MB f16
  unsigned int* coords = (unsigned int*)(ws + 16777216);       // 67.1 MB u32
  ushort_t*     WpH    = ws + 50331648;                        // 221 KB
  unsigned int* WpC    = (unsigned int*)(ws + 50331648 + 110592); // 147 KB

  k_repack  <<<dim3(576),  256, 0, stream>>>(Ws, Wx, Wy, WpH, WpC);
  k_conv_all<<<dim3(1024), 512, 0, stream>>>(x, WpH, WpC, bs, bx, by, score, coords);
  k_sample  <<<dim3(1024), 256, 0, stream>>>(score, coords, out);
}

// Round 10
// 263.939 us; speedup vs baseline: 1.0177x; 1.0177x over previous
//
#include <hip/hip_runtime.h>
#include <stdint.h>

typedef unsigned short ushort_t;
typedef _Float16 f16x8 __attribute__((ext_vector_type(8)));
typedef _Float16 f16x4 __attribute__((ext_vector_type(4)));
typedef float f32x4 __attribute__((ext_vector_type(4)));
typedef float f32x16 __attribute__((ext_vector_type(16)));
typedef int   i32x4 __attribute__((ext_vector_type(4)));
typedef int   i32x16 __attribute__((ext_vector_type(16)));
typedef unsigned int uint4v __attribute__((ext_vector_type(4)));

#define HW_ 16384
#define MFMAH  __builtin_amdgcn_mfma_f32_32x32x16_f16
#define MFMAI8 __builtin_amdgcn_mfma_i32_32x32x32_i8
#define C_CORR (1.0f/16777216.0f)   // 2^-24: Al8(2^15)*Wh8(2^9) and Ah8(2^4)*Wl8(2^20)

__device__ __forceinline__ ushort_t f2h_bits(float f){
  union { _Float16 h; ushort_t u; } c; c.h = (_Float16)f; return c.u;
}
__device__ __forceinline__ float h_bits2f(ushort_t u){
  union { _Float16 h; ushort_t u; } c; c.u = u; return (float)c.h;
}
__device__ __forceinline__ int clamp8(int v){ return min(max(v,-127),127); }

// ---------------------------------------------------------------------------
// WpH (f16 bits): ((conv*2+mh)*36 + ks16)*512 + lane*8 + j
//   conv 0=Ws 1=Wx 2=Wy; co = mh*32+(lane&31); tap = ks16>>2;
//   ci = (ks16&3)*16 + (lane>>5)*8 + j.
// WpC (i8 dwords): ((g*2+mh)*18 + ks32)*256 + lane*4 + j4
//   g 0=Wh8x 1=Wh8y 2=Wl8x 3=Wl8y; tap = ks32>>1;
//   ci = (ks32&1)*32 + (lane>>5)*16 + j4*4 + bb.
// ---------------------------------------------------------------------------
__global__ __launch_bounds__(256) void k_repack(
    const float* __restrict__ Ws, const float* __restrict__ Wx,
    const float* __restrict__ Wy,
    ushort_t* __restrict__ WpH, unsigned int* __restrict__ WpC){
  int e = blockIdx.x*256 + threadIdx.x;
  if (e < 110592){
    int j = e & 7; int lane = (e >> 3) & 63; int rest = e >> 9;
    int ks = rest % 36; int cm = rest / 36;
    int conv = cm >> 1; int mh = cm & 1;
    int co = mh*32 + (lane & 31);
    int tap = ks >> 2;
    int ci = (ks & 3)*16 + ((lane >> 5) & 1)*8 + j;
    const float* src = (conv==0) ? Ws : (conv==1) ? Wx : Wy;
    WpH[e] = f2h_bits(src[(co*64 + ci)*9 + tap]);
  } else if (e < 110592 + 36864){
    int d = e - 110592;
    int j4 = d & 3; int lane = (d >> 2) & 63; int rest = d >> 8;
    int ks = rest % 18; int gm = rest / 18;
    int g = gm >> 1; int mh = gm & 1;
    int co = mh*32 + (lane & 31);
    int tap = ks >> 1;
    const float* src = (g==0 || g==2) ? Wx : Wy;
    unsigned dd = 0;
    #pragma unroll
    for (int bb=0; bb<4; bb++){
      int ci = (ks & 1)*32 + ((lane >> 5) & 1)*16 + j4*4 + bb;
      float w = src[(co*64 + ci)*9 + tap];
      int v;
      if (g < 2){
        v = clamp8((int)rintf(w*512.f));
      } else {
        float wl = w - h_bits2f(f2h_bits(w));
        v = clamp8((int)rintf(wl*1048576.f));
      }
      dd |= ((unsigned)(v & 255)) << (bb*8);
    }
    WpC[d] = dd;
  }
}

// ---------------------------------------------------------------------------
// Fused conv. R9 post-mortem: LDS-staged async weights ~flat -> weight-load
// LATENCY was not the stall. Remaining model: the 2 waves/SIMD run in
// LOCKSTEP (same code, same start), so both hit their load/ds_read phase
// simultaneously -> neither hides under the other's 640-cyc MFMA burst
// (R9's extra barriers tightened lockstep and got slightly worse).
// Fix: ANTI-PHASE scheduling. Split each iter into P1={f16 loads+12 f16
// MFMA} and P2={i8 loads+8 i8 MFMA}; waves with grp=(wid>>2)&1==0 run
// P1->P2, their SIMD partners (wid+4) run P2->P1, sched_barrier(0) pinning
// the boundary. Per-accumulator MFMA order unchanged -> bit-identical.
// Base = R8: reg-direct weights, no in-loop barriers, NT stores, coords
// encode (i+4)*480. LDS [10][34][64] x {f16,i8,i8} = 87 KB, 1 block/CU.
// Grid 1024 XCD-swizzled: all WGs of batch b on XCD b&7.
// ---------------------------------------------------------------------------
__global__ __launch_bounds__(512, 2) void k_conv_all(
    const float* __restrict__ x,
    const ushort_t* __restrict__ WpH, const unsigned int* __restrict__ WpC,
    const float* __restrict__ bs, const float* __restrict__ bx,
    const float* __restrict__ by,
    ushort_t* __restrict__ score, unsigned int* __restrict__ coords){
  int bid = blockIdx.x;
  int idx = bid >> 3;
  int b = (bid & 7) + 8*(idx >> 6);     // 64 blocks per batch
  int rest = idx & 63;
  int h0 = (rest >> 2)*8;               // 16 h-tiles of 8 rows
  int wq = (rest & 3)*32;
  int t = threadIdx.x; int lane = t & 63; int wid = t >> 6;   // wid 0..7
  int n = lane & 31; int kh = lane >> 5;
  __shared__ __align__(16) _Float16 BH[10*34*64];   // 43520 B
  __shared__ __align__(16) char BAl[10*34*64];      // 21760 B
  __shared__ __align__(16) char BAh[10*34*64];      // 21760 B

  // ---- staging: 1360 items of 16 ci (10 rows x 4 q x 34 w1), 3 passes ----
  const float* xb = x + (size_t)b*64*HW_;
  #pragma unroll
  for (int it=0; it<3; it++){
    int f = it*512 + t;
    if (f < 1360){
      int r = f/136; int rem = f - r*136; int q = rem/34; int w1 = rem - q*34;
      int y = h0 + r - 1; int w = wq + w1 - 1;
      f16x8 h0v = {0,0,0,0,0,0,0,0}, h1v = {0,0,0,0,0,0,0,0};
      unsigned alb[4] = {0,0,0,0}, ahb[4] = {0,0,0,0};
      if (((unsigned)y < 128u) & ((unsigned)w < 128u)){
        const float* p = xb + (size_t)(q*16)*HW_ + y*128 + w;
        #pragma unroll
        for (int j=0; j<16; j++){
          float v = p[(size_t)j*HW_];
          _Float16 hv = (_Float16)v;
          float al = v - (float)hv;
          int a8 = clamp8((int)rintf(al*32768.f));
          int x8 = clamp8((int)rintf(v*16.f));
          if (j < 8) h0v[j] = hv; else h1v[j-8] = hv;
          alb[j>>2] |= ((unsigned)(a8 & 255)) << ((j&3)*8);
          ahb[j>>2] |= ((unsigned)(x8 & 255)) << ((j&3)*8);
        }
      }
      int base = (r*34 + w1)*64;
      int sw = w1 & 7;
      *(f16x8*)&BH[base + (((2*q)   ^ sw) << 3)] = h0v;
      *(f16x8*)&BH[base + (((2*q+1) ^ sw) << 3)] = h1v;
      int islot = ((q + (w1 >> 1)) & 3) << 4;
      i32x4 av  = {(int)alb[0],(int)alb[1],(int)alb[2],(int)alb[3]};
      i32x4 hv2 = {(int)ahb[0],(int)ahb[1],(int)ahb[2],(int)ahb[3]};
      *(i32x4*)&BAl[base + islot] = av;
      *(i32x4*)&BAh[base + islot] = hv2;
    }
  }
  __syncthreads();

  int mh = wid & 1;      // co half
  int pp = wid >> 1;     // row-pair within tile (0..3)
  int grp = (wid >> 2) & 1;   // SIMD partners (wid, wid+4) differ in grp

  f32x16 acc_s0, acc_gx0, acc_gy0, acc_s1, acc_gx1, acc_gy1;
  i32x16 c_x0, c_y0, c_x1, c_y1;
  #pragma unroll
  for (int r2=0; r2<16; r2++){
    acc_s0[r2]=0.f; acc_gx0[r2]=0.f; acc_gy0[r2]=0.f;
    acc_s1[r2]=0.f; acc_gx1[r2]=0.f; acc_gy1[r2]=0.f;
    c_x0[r2]=0; c_y0[r2]=0; c_x1[r2]=0; c_y1[r2]=0;
  }

  // incremented weight pointers: f16 advance 1024 elem (2 ks16) per ks-iter,
  // i8 advance 1024 B (1 ks32) per ks-iter.
  const ushort_t* pS = WpH + ((0*2+mh)*36)*512 + lane*8;
  const ushort_t* pX = WpH + ((1*2+mh)*36)*512 + lane*8;
  const ushort_t* pY = WpH + ((2*2+mh)*36)*512 + lane*8;
  const char* pWhx = (const char*)WpC + (((0*2+mh)*18)*64 + lane)*16;
  const char* pWhy = (const char*)WpC + (((1*2+mh)*18)*64 + lane)*16;
  const char* pWlx = (const char*)WpC + (((2*2+mh)*18)*64 + lane)*16;
  const char* pWly = (const char*)WpC + (((3*2+mh)*18)*64 + lane)*16;

  // phase P1: f16 weights + f16 input frags -> 12 f16 MFMAs (rows 0,1)
  #define PH_F16 do {                                                   \
    f16x8 sA = *(const f16x8*)pS;                                       \
    f16x8 sB = *(const f16x8*)(pS + 512);                               \
    f16x8 xA = *(const f16x8*)pX;                                       \
    f16x8 xB = *(const f16x8*)(pX + 512);                               \
    f16x8 yA = *(const f16x8*)pY;                                       \
    f16x8 yB = *(const f16x8*)(pY + 512);                               \
    f16x8 bA0 = *(const f16x8*)&BH[rowb0 + off0];                       \
    f16x8 bB0 = *(const f16x8*)&BH[rowb0 + off1];                       \
    f16x8 bA1 = *(const f16x8*)&BH[rowb1 + off0];                       \
    f16x8 bB1 = *(const f16x8*)&BH[rowb1 + off1];                       \
    acc_s0  = MFMAH(sA, bA0, acc_s0, 0,0,0);                            \
    acc_gx0 = MFMAH(xA, bA0, acc_gx0,0,0,0);                            \
    acc_gy0 = MFMAH(yA, bA0, acc_gy0,0,0,0);                            \
    acc_s0  = MFMAH(sB, bB0, acc_s0, 0,0,0);                            \
    acc_gx0 = MFMAH(xB, bB0, acc_gx0,0,0,0);                            \
    acc_gy0 = MFMAH(yB, bB0, acc_gy0,0,0,0);                            \
    acc_s1  = MFMAH(sA, bA1, acc_s1, 0,0,0);                            \
    acc_gx1 = MFMAH(xA, bA1, acc_gx1,0,0,0);                            \
    acc_gy1 = MFMAH(yA, bA1, acc_gy1,0,0,0);                            \
    acc_s1  = MFMAH(sB, bB1, acc_s1, 0,0,0);                            \
    acc_gx1 = MFMAH(xB, bB1, acc_gx1,0,0,0);                            \
    acc_gy1 = MFMAH(yB, bB1, acc_gy1,0,0,0);                            \
  } while(0)

  // phase P2: i8 weights + i8 input frags -> 8 i8 MFMAs (rows 0,1)
  #define PH_I8 do {                                                    \
    i32x4 whx = *(const i32x4*)pWhx;                                    \
    i32x4 why = *(const i32x4*)pWhy;                                    \
    i32x4 wlx = *(const i32x4*)pWlx;                                    \
    i32x4 wly = *(const i32x4*)pWly;                                    \
    i32x4 bal0 = *(const i32x4*)&BAl[rowb0 + islot];                    \
    i32x4 bah0 = *(const i32x4*)&BAh[rowb0 + islot];                    \
    i32x4 bal1 = *(const i32x4*)&BAl[rowb1 + islot];                    \
    i32x4 bah1 = *(const i32x4*)&BAh[rowb1 + islot];                    \
    c_x0 = MFMAI8(whx, bal0, c_x0, 0,0,0);                              \
    c_x0 = MFMAI8(wlx, bah0, c_x0, 0,0,0);                              \
    c_y0 = MFMAI8(why, bal0, c_y0, 0,0,0);                              \
    c_y0 = MFMAI8(wly, bah0, c_y0, 0,0,0);                              \
    c_x1 = MFMAI8(whx, bal1, c_x1, 0,0,0);                              \
    c_x1 = MFMAI8(wlx, bah1, c_x1, 0,0,0);                              \
    c_y1 = MFMAI8(why, bal1, c_y1, 0,0,0);                              \
    c_y1 = MFMAI8(wly, bah1, c_y1, 0,0,0);                              \
  } while(0)

  #define ITER_HEAD                                                     \
    int tap = ks >> 1; int qp = ks & 1;                                 \
    int rb = tap/3; int dw = tap - rb*3 - 1;                            \
    int w1 = n + dw + 1;                                                \
    int sw = w1 & 7;                                                    \
    int rowb0 = ((rb + 2*pp)*34 + w1)*64;                               \
    int rowb1 = rowb0 + 34*64;                                          \
    int off0  = ((qp*4 + kh)     ^ sw) << 3;                            \
    int off1  = ((qp*4 + 2 + kh) ^ sw) << 3;                            \
    int islot = (((qp*2 + kh) + (w1 >> 1)) & 3) << 4;

  #define ITER_ADV                                                      \
    pS += 1024; pX += 1024; pY += 1024;                                 \
    pWhx += 1024; pWhy += 1024; pWlx += 1024; pWly += 1024;

  if (grp == 0){
    #pragma unroll 1
    for (int ks=0; ks<18; ++ks){
      ITER_HEAD
      PH_F16;
      __builtin_amdgcn_sched_barrier(0);
      PH_I8;
      ITER_ADV
    }
  } else {
    #pragma unroll 1
    for (int ks=0; ks<18; ++ks){
      ITER_HEAD
      PH_I8;
      __builtin_amdgcn_sched_barrier(0);
      PH_F16;
      ITER_ADV
    }
  }
  #undef PH_F16
  #undef PH_I8
  #undef ITER_HEAD
  #undef ITER_ADV

  // epilogue: score f16 + packed u16 coords ((i+4)*480 exact shift for the
  // padded-plane sampler). NT stores keep the write stream out of L2.
  int w = wq + n;
  int hb = h0 + 2*pp;
  #define EPILOG(AS_, AX_, AY_, CX_, CY_, H_) do {                      \
    ushort_t*     sb = score  + (size_t)b*64*HW_ + (H_)*128 + w;        \
    unsigned int* cb = coords + (size_t)b*64*HW_ + (H_)*128 + w;        \
    _Pragma("unroll")                                                   \
    for (int reg=0; reg<16; reg++){                                     \
      int col = mh*32 + (reg & 3) + 8*(reg >> 2) + 4*kh;                \
      float sv = AS_[reg] + bs[col];                                    \
      float gx = AX_[reg] + (float)CX_[reg]*C_CORR + bx[col];           \
      float gy = AY_[reg] + (float)CY_[reg]*C_CORR + by[col];           \
      __builtin_nontemporal_store(f2h_bits(sv), &sb[(size_t)col*HW_]);  \
      float ixf = fminf(fmaxf((gx + 1.f)*64.f - 0.5f, -2.f), 129.f);    \
      float iyf = fminf(fmaxf((gy + 1.f)*64.f - 0.5f, -2.f), 129.f);    \
      unsigned ux = (unsigned)rintf((ixf + 4.f)*480.f);                 \
      unsigned uy = (unsigned)rintf((iyf + 4.f)*480.f);                 \
      __builtin_nontemporal_store(ux | (uy << 16), &cb[(size_t)col*HW_]); \
    }                                                                   \
  } while(0)
  EPILOG(acc_s0, acc_gx0, acc_gy0, c_x0, c_y0, hb);
  EPILOG(acc_s1, acc_gx1, acc_gy1, c_x1, c_y1, hb+1);
  #undef EPILOG
}

// ---------------------------------------------------------------------------
// Sampler v2: zero-padded LDS plane -> branchless, maskless bilinear.
// Plane: 135 rows x 136 u16 (stride 68 dwords), interior at [y+4][x+4],
// borders zero (== grid_sample zeros padding). Coords are (i+4)*480 u16.
// 36720 B LDS -> 4 blocks/CU. Grid 1024 XCD-swizzled.
// ---------------------------------------------------------------------------
__global__ __launch_bounds__(256, 4) void k_sample(
    const ushort_t* __restrict__ score, const unsigned int* __restrict__ coords,
    float* __restrict__ out){
  int bid = blockIdx.x;
  int idx = bid >> 3;
  int b  = (bid & 7) + 8*(idx >> 6);
  int co = idx & 63;
  int t = threadIdx.x;
  __shared__ __align__(16) unsigned int SC32[135*68];   // 36720 B

  // zero-fill whole plane (borders must be 0; interior overwritten below)
  #pragma unroll
  for (int i=0;i<9;i++){
    int c = i*256 + t;
    if (c < 2295){
      uint4v z = {0,0,0,0};
      *(uint4v*)&SC32[c*4] = z;
    }
  }
  __syncthreads();

  const ushort_t* sp = score + (size_t)(b*64 + co)*HW_;
  ushort_t* scu = (ushort_t*)SC32;
  #pragma unroll
  for (int i=0;i<8;i++){
    int c = i*256 + t;
    int y = c >> 4; int xg = (c & 15)*8;
    f16x8 v = __builtin_nontemporal_load((const f16x8*)(sp + c*8));
    f16x4 lo = {v[0],v[1],v[2],v[3]};
    f16x4 hi = {v[4],v[5],v[6],v[7]};
    *(f16x4*)&scu[(y+4)*136 + (xg+4)] = lo;   // 8B-aligned ds_write_b64
    *(f16x4*)&scu[(y+4)*136 + (xg+8)] = hi;
  }
  __syncthreads();

  const unsigned int* cp = coords + (size_t)(b*64 + co)*HW_;
  float* op = out + (size_t)(b*64 + co)*HW_;
  uint4v ca  = __builtin_nontemporal_load((const uint4v*)(cp + t*8));
  uint4v cb2 = __builtin_nontemporal_load((const uint4v*)(cp + t*8 + 4));
  #pragma unroll 1
  for (int k=0;k<8;k++){
    int px = (k*256 + t)*8;
    uint4v na, nb;
    if (k < 7){
      na = __builtin_nontemporal_load((const uint4v*)(cp + px + 2048));
      nb = __builtin_nontemporal_load((const uint4v*)(cp + px + 2052));
    }
    float r[8];
    #pragma unroll
    for (int j=0;j<8;j++){
      unsigned u = (j < 4) ? ca[j] : cb2[j-4];
      float ixp = (float)(u & 0xffffu)*(1.0f/480.0f);   // padded coord [2,133]
      float iyp = (float)(u >> 16)   *(1.0f/480.0f);
      float x0f = floorf(ixp), y0f = floorf(iyp);
      int x0 = (int)x0f, y0 = (int)y0f;                 // 2..133, always valid
      float wx1 = ixp - x0f, wy1 = iyp - y0f;
      float wx0 = 1.f - wx1, wy0 = 1.f - wy1;
      int base = y0*68 + (x0 >> 1);
      unsigned d00 = SC32[base],    d01 = SC32[base+1];
      unsigned d10 = SC32[base+68], d11 = SC32[base+69];
      unsigned sh = (unsigned)(x0 & 1) << 4;
      unsigned p0 = (unsigned)(((((unsigned long long)d01) << 32) | d00) >> sh);
      unsigned p1 = (unsigned)(((((unsigned long long)d11) << 32) | d10) >> sh);
      float v00 = h_bits2f((ushort_t)(p0 & 0xffffu));
      float v01 = h_bits2f((ushort_t)(p0 >> 16));
      float v10 = h_bits2f((ushort_t)(p1 & 0xffffu));
      float v11 = h_bits2f((ushort_t)(p1 >> 16));
      r[j] = wy0*(v00*wx0 + v01*wx1) + wy1*(v10*wx0 + v11*wx1);
    }
    f32x4 r0 = {r[0],r[1],r[2],r[3]};
    f32x4 r1 = {r[4],r[5],r[6],r[7]};
    __builtin_nontemporal_store(r0, (f32x4*)(op + px));
    __builtin_nontemporal_store(r1, (f32x4*)(op + px + 4));
    ca = na; cb2 = nb;
  }
}

// ---------------------------------------------------------------------------
extern "C" void kernel_launch(void* const* d_in, const int* in_sizes, int n_in,
                              void* d_out, int out_size, void* d_ws, size_t ws_size,
                              hipStream_t stream){
  const float* x  = (const float*)d_in[0];
  const float* Ws = (const float*)d_in[1];
  const float* bs = (const float*)d_in[2];
  const float* Wx = (const float*)d_in[3];
  const float* bx = (const float*)d_in[4];
  const float* Wy = (const float*)d_in[5];
  const float* by = (const float*)d_in[6];
  float* out = (float*)d_out;
  ushort_t* ws  = (ushort_t*)d_ws;
  ushort_t*     score  = ws;                                   // 33.5 MB f16
  unsigned int* coords = (unsigned int*)(ws + 16777216);       // 67.1 MB u32
  ushort_t*     WpH    = ws + 50331648;                        // 221 KB
  unsigned int* WpC    = (unsigned int*)(ws + 50331648 + 110592); // 147 KB

  k_repack  <<<dim3(576),  256, 0, stream>>>(Ws, Wx, Wy, WpH, WpC);
  k_conv_all<<<dim3(1024), 512, 0, stream>>>(x, WpH, WpC, bs, bx, by, score, coords);
  k_sample  <<<dim3(1024), 256, 0, stream>>>(score, coords, out);
}